// Round 9
// baseline (88.330 us; speedup 1.0000x reference)
//
#include <hip/hip_runtime.h>
#include <math.h>

#define CHUNK 512      // simplices per ect block
#define RSL 8          // reduction slices
#define FPS 32768.0f   // fixed-point scale 2^15 for transition sums

// K1: raw-order saturation-split ECT, heights computed on the fly from x.v
// (no nh buffer). Block = (chunk c of 512 simplices, theta-half hf).
// Thread (srow 0..15, t16 0..15): simplex m = start+srow+16k, theta tt.
// LDS hist [arr][g][bin][t16] = 32 KB; int atomics only (deterministic).
// Simplices ordered [nodes | edges | faces] -> three branch-free loops.
// Flush = plain coalesced int4 stores into partial[bid][8192].
// Block 0 also resets the redfin ticket (stream-ordered, pre-redfin).
__global__ __launch_bounds__(256) void ect_kernel(const float* __restrict__ x,
    const float* __restrict__ v, const int* __restrict__ ei,
    const int* __restrict__ face, const int* __restrict__ batch,
    const float* __restrict__ lin, const int* __restrict__ scale_p,
    int* __restrict__ partial, int* __restrict__ done,
    int N, int E, int F, int M) {
  __shared__ alignas(16) int hist[8192];  // arr*4096 + g*512 + bin*16 + t16
  int tid = threadIdx.x, bid = blockIdx.x;
  if (bid == 0 && tid == 0)
    __hip_atomic_store(done, 0, __ATOMIC_RELAXED, __HIP_MEMORY_SCOPE_AGENT);
  int c = bid >> 1, hf = bid & 1;
#pragma unroll
  for (int i = 0; i < 8; ++i)
    ((int4*)hist)[tid + 256 * i] = int4{0, 0, 0, 0};
  __syncthreads();

  int t16 = tid & 15, srow = tid >> 4;    // srow 0..15
  int tt = (hf << 4) + t16;               // global theta
  float v0 = v[tt], v1 = v[32 + tt], v2 = v[64 + tt];
  int start = c * CHUNK;
  int end = min(start + CHUNK, M);

  float scale = (float)scale_p[0];
  float lin0 = lin[0];
  float step = (lin[31] - lin0) * (1.f / 31.f);
  float istep = 1.f / step;
  float Cl = scale * step * 1.44269504088896f;  // log2-slope per bin
  float w = 13.f / (scale * step);              // transition half-width (bins)

  auto dot3 = [&](int n) {
    return fmaf(x[3 * n], v0, fmaf(x[3 * n + 1], v1, x[3 * n + 2] * v2));
  };
  auto deposit = [&](float h, int g, int isn) {
    float kf = (h - lin0) * istep;
    int b0 = (int)ceilf(kf - w);
    int b1 = (int)floorf(kf + w);
    int fs = max(b1 + 1, 0);
    int gb = g << 9;
    if (fs <= 31) atomicAdd(&hist[gb + (fs << 4) + t16], isn);
    float q = Cl * kf;
    float fsn = (float)isn;
    int blo = max(b0, 0), bhi = min(b1, 31);
    for (int b = blo; b <= bhi; ++b) {
      float e2 = __builtin_amdgcn_exp2f(fmaf(-Cl, (float)b, q));
      float val = fsn * __builtin_amdgcn_rcpf(1.f + e2);
      atomicAdd(&hist[4096 + gb + (b << 4) + t16], (int)rintf(val * FPS));
    }
  };

  // nodes
  int e0 = min(end, N);
  for (int m = start + srow; m < e0; m += 16)
    deposit(dot3(m), batch[m], 1);
  // edges (max over 2 endpoints, sign -1)
  int s1 = max(start, N), e1 = min(end, N + E);
  for (int m = s1 + srow; m < e1; m += 16) {
    int e = m - N;
    int n0 = ei[e], n1 = ei[E + e];
    deposit(fmaxf(dot3(n0), dot3(n1)), batch[n0], -1);
  }
  // faces (max over 3 vertices, sign +1)
  int s2 = max(start, N + E);
  for (int m = s2 + srow; m < end; m += 16) {
    int f = m - N - E;
    int n0 = face[f], n1 = face[F + f], n2 = face[2 * F + f];
    deposit(fmaxf(fmaxf(dot3(n0), dot3(n1)), dot3(n2)), batch[n0], 1);
  }
  __syncthreads();
  int4* dst = (int4*)(partial + (size_t)bid * 8192);
  const int4* src = (const int4*)hist;
#pragma unroll
  for (int i = 0; i < 8; ++i)
    dst[tid + 256 * i] = src[tid + 256 * i];
}

// K2: tree reduce over chunks + fused last-block finisher.
// 512 blocks (exactly 2/CU): s = bid>>6 (0..7), cg = bid&63; cid = cg*256+tid.
// cid = hf*8192 + (arr*4096 + g*512 + bin*16 + t16).
// Last block: per (g,theta) column prefix of markers over bins, add
// fractional transitions, per-graph max (32-lane shuffle), normalize, out.
__global__ __launch_bounds__(256) void redfin_kernel(const int* __restrict__ partial,
    int* __restrict__ part2, int* __restrict__ done, float* __restrict__ out,
    int nchunk) {
  int tid = threadIdx.x, bid = blockIdx.x;
  int s = bid >> 6, cg = bid & 63;
  int cid = cg * 256 + tid;
  int hf = cid >> 13, j = cid & 8191;
  int sum = 0;
  for (int cc = s; cc < nchunk; cc += RSL)
    sum += partial[(size_t)(cc * 2 + hf) * 8192 + j];
  part2[s * 16384 + cid] = sum;

  __threadfence();
  __shared__ int amLast;
  if (tid == 0) amLast = (atomicAdd(done, 1) == 511);
  __syncthreads();
  if (!amLast) return;

  int g = tid >> 5, t = tid & 31;
  int hf2 = t >> 4, t16 = t & 15;
  int base_c = (hf2 << 13) + (g << 9) + t16;  // + (k<<4); transitions +4096
  float r[32];
  int runc = 0;
  float mx = -1e30f;
#pragma unroll
  for (int k = 0; k < 32; ++k) {
    int sc = 0, sa = 0;
#pragma unroll
    for (int s2 = 0; s2 < RSL; ++s2) {
      sc += __hip_atomic_load(&part2[s2 * 16384 + base_c + (k << 4)],
                              __ATOMIC_RELAXED, __HIP_MEMORY_SCOPE_AGENT);
      sa += __hip_atomic_load(&part2[s2 * 16384 + base_c + 4096 + (k << 4)],
                              __ATOMIC_RELAXED, __HIP_MEMORY_SCOPE_AGENT);
    }
    runc += sc;
    r[k] = (float)runc + (float)sa * (1.f / FPS);
    mx = fmaxf(mx, r[k]);
  }
#pragma unroll
  for (int off = 1; off < 32; off <<= 1) mx = fmaxf(mx, __shfl_xor(mx, off));
  float imx = 1.f / mx;
#pragma unroll
  for (int k = 0; k < 32; ++k)
    out[(g << 10) + (k << 5) + t] = r[k] * imx;
}

extern "C" void kernel_launch(void* const* d_in, const int* in_sizes, int n_in,
                              void* d_out, int out_size, void* d_ws, size_t ws_size,
                              hipStream_t stream) {
  const float* x     = (const float*)d_in[0];
  const float* v     = (const float*)d_in[1];
  const float* lin   = (const float*)d_in[2];
  const int*   ei    = (const int*)d_in[3];
  const int*   face  = (const int*)d_in[4];
  const int*   batch = (const int*)d_in[5];
  const int*   scale = (const int*)d_in[6];
  const int N = in_sizes[5];
  const int E = in_sizes[3] / 2;
  const int F = in_sizes[4] / 3;
  const int M = N + E + F;
  const int nchunk = (M + CHUNK - 1) / CHUNK;

  int* partial = (int*)d_ws;                              // 2*nchunk*8192 ints
  int* part2   = partial + (size_t)2 * nchunk * 8192;     // RSL*16384 ints
  int* done    = part2 + RSL * 16384;                     // 1 int

  ect_kernel<<<2 * nchunk, 256, 0, stream>>>(x, v, ei, face, batch, lin, scale,
                                             partial, done, N, E, F, M);
  redfin_kernel<<<64 * RSL, 256, 0, stream>>>(partial, part2, done,
                                              (float*)d_out, nchunk);
}

// Round 10
// 42.267 us; speedup vs baseline: 2.0898x; 2.0898x over previous
//
#include <hip/hip_runtime.h>
#include <math.h>

#define NCH 256        // number of simplex chunks (grid_ect = 2*NCH = 512)
#define RSL 8          // reduction slices
#define FPS 32768.0f   // fixed-point scale 2^15 for transition sums

// K1: raw-order saturation-split ECT, heights computed on the fly from x.v.
// Block = (chunk c, theta-half hf); thread (srow 0..15, t16 0..15).
// LDS hist [arr][g][bin][t16] = 32 KB; LDS int atomics only (deterministic;
// 16 t16-lanes of each quarter-wave hit distinct addresses).
// Simplices ordered [nodes | edges | faces] -> three branch-free loops.
// Flush = plain coalesced int4 stores into partial[bid][8192].
__global__ __launch_bounds__(256) void ect_kernel(const float* __restrict__ x,
    const float* __restrict__ v, const int* __restrict__ ei,
    const int* __restrict__ face, const int* __restrict__ batch,
    const float* __restrict__ lin, const int* __restrict__ scale_p,
    int* __restrict__ partial, int N, int E, int F, int M, int csz) {
  __shared__ alignas(16) int hist[8192];  // arr*4096 + g*512 + bin*16 + t16
  int tid = threadIdx.x, bid = blockIdx.x;
  int c = bid >> 1, hf = bid & 1;
#pragma unroll
  for (int i = 0; i < 8; ++i)
    ((int4*)hist)[tid + 256 * i] = int4{0, 0, 0, 0};
  __syncthreads();

  int t16 = tid & 15, srow = tid >> 4;    // srow 0..15
  int tt = (hf << 4) + t16;               // global theta
  float v0 = v[tt], v1 = v[32 + tt], v2 = v[64 + tt];
  int start = c * csz;
  int end = min(start + csz, M);

  float scale = (float)scale_p[0];
  float lin0 = lin[0];
  float step = (lin[31] - lin0) * (1.f / 31.f);
  float istep = 1.f / step;
  float Cl = scale * step * 1.44269504088896f;  // log2-slope per bin
  float w = 13.f / (scale * step);              // transition half-width (bins)

  auto dot3 = [&](int n) {
    return fmaf(x[3 * n], v0, fmaf(x[3 * n + 1], v1, x[3 * n + 2] * v2));
  };
  auto deposit = [&](float h, int g, int isn) {
    float kf = (h - lin0) * istep;
    int b0 = (int)ceilf(kf - w);
    int b1 = (int)floorf(kf + w);
    int fs = max(b1 + 1, 0);
    int gb = g << 9;
    if (fs <= 31) atomicAdd(&hist[gb + (fs << 4) + t16], isn);
    float q = Cl * kf;
    float fsn = (float)isn;
    int blo = max(b0, 0), bhi = min(b1, 31);
    for (int b = blo; b <= bhi; ++b) {
      float e2 = __builtin_amdgcn_exp2f(fmaf(-Cl, (float)b, q));
      float val = fsn * __builtin_amdgcn_rcpf(1.f + e2);
      atomicAdd(&hist[4096 + gb + (b << 4) + t16], (int)rintf(val * FPS));
    }
  };

  // nodes
  int e0 = min(end, N);
  for (int m = start + srow; m < e0; m += 16)
    deposit(dot3(m), batch[m], 1);
  // edges (max over 2 endpoints, sign -1)
  int s1 = max(start, N), e1 = min(end, N + E);
  for (int m = s1 + srow; m < e1; m += 16) {
    int e = m - N;
    int n0 = ei[e], n1 = ei[E + e];
    deposit(fmaxf(dot3(n0), dot3(n1)), batch[n0], -1);
  }
  // faces (max over 3 vertices, sign +1)
  int s2 = max(start, N + E);
  for (int m = s2 + srow; m < end; m += 16) {
    int f = m - N - E;
    int n0 = face[f], n1 = face[F + f], n2 = face[2 * F + f];
    deposit(fmaxf(fmaxf(dot3(n0), dot3(n1)), dot3(n2)), batch[n0], 1);
  }
  __syncthreads();
  int4* dst = (int4*)(partial + (size_t)bid * 8192);
  const int4* src = (const int4*)hist;
#pragma unroll
  for (int i = 0; i < 8; ++i)
    dst[tid + 256 * i] = src[tid + 256 * i];
}

// K2: tree reduce over chunks. 512 blocks: s = bid>>6 (0..7), cg = bid&63;
// cell cid = cg*256+tid; cid = hf*8192 + (arr*4096 + g*512 + bin*16 + t16).
// Plain coalesced loads/stores, no atomics.
__global__ __launch_bounds__(256) void reduce_kernel(const int* __restrict__ partial,
    int* __restrict__ part2) {
  int tid = threadIdx.x, bid = blockIdx.x;
  int s = bid >> 6, cg = bid & 63;
  int cid = cg * 256 + tid;
  int hf = cid >> 13, j = cid & 8191;
  int sum = 0;
  for (int cc = s; cc < NCH; cc += RSL)
    sum += partial[(size_t)(cc * 2 + hf) * 8192 + j];
  part2[s * 16384 + cid] = sum;
}

// K3: per-graph block (8 x 1024): sum RSL slices (plain loads), Hillis-Steele
// prefix of markers over bins, add fractional transitions, per-graph max,
// normalize, write out.
__global__ __launch_bounds__(1024) void fin_kernel(const int* __restrict__ part2,
    float* __restrict__ out) {
  __shared__ float sP[32][33];
  __shared__ float wmax[16];
  int g = blockIdx.x, tid = threadIdx.x;
  int b = tid >> 5, t = tid & 31;
  int hf = t >> 4, t16 = t & 15;
  int jc = (hf << 13) + (g << 9) + (b << 4) + t16;  // marker cell
  int ja = jc + 4096;                               // transition cell
  int sc = 0, sa = 0;
#pragma unroll
  for (int s = 0; s < RSL; ++s) {
    sc += part2[s * 16384 + jc];
    sa += part2[s * 16384 + ja];
  }
  sP[b][t] = (float)sc;
  __syncthreads();
#pragma unroll
  for (int st = 1; st < 32; st <<= 1) {
    float add = (b >= st) ? sP[b - st][t] : 0.f;
    __syncthreads();
    sP[b][t] += add;
    __syncthreads();
  }
  float r = sP[b][t] + (float)sa * (1.f / FPS);
  float m = r;
#pragma unroll
  for (int off = 32; off > 0; off >>= 1) m = fmaxf(m, __shfl_down(m, off));
  if ((tid & 63) == 0) wmax[tid >> 6] = m;
  __syncthreads();
  if (tid == 0) {
    float mm = wmax[0];
#pragma unroll
    for (int ww = 1; ww < 16; ++ww) mm = fmaxf(mm, wmax[ww]);
    wmax[0] = mm;
  }
  __syncthreads();
  out[(size_t)g * 1024 + tid] = r / wmax[0];
}

extern "C" void kernel_launch(void* const* d_in, const int* in_sizes, int n_in,
                              void* d_out, int out_size, void* d_ws, size_t ws_size,
                              hipStream_t stream) {
  const float* x     = (const float*)d_in[0];
  const float* v     = (const float*)d_in[1];
  const float* lin   = (const float*)d_in[2];
  const int*   ei    = (const int*)d_in[3];
  const int*   face  = (const int*)d_in[4];
  const int*   batch = (const int*)d_in[5];
  const int*   scale = (const int*)d_in[6];
  const int N = in_sizes[5];
  const int E = in_sizes[3] / 2;
  const int F = in_sizes[4] / 3;
  const int M = N + E + F;
  const int csz = (M + NCH - 1) / NCH;   // simplices per chunk (~704)

  int* partial = (int*)d_ws;                          // 2*NCH*8192 ints
  int* part2   = partial + (size_t)2 * NCH * 8192;    // RSL*16384 ints

  ect_kernel<<<2 * NCH, 256, 0, stream>>>(x, v, ei, face, batch, lin, scale,
                                          partial, N, E, F, M, csz);
  reduce_kernel<<<64 * RSL, 256, 0, stream>>>(partial, part2);
  fin_kernel<<<8, 1024, 0, stream>>>(part2, (float*)d_out);
}

// Round 11
// 35.274 us; speedup vs baseline: 2.5041x; 1.1982x over previous
//
#include <hip/hip_runtime.h>
#include <math.h>

#define NCH 256        // number of simplex chunks (grid_ect = 2*NCH = 512)
#define RSL 8          // reduction slices
#define FPS 32768.0f   // fixed-point scale 2^15 for transition sums

// K1: raw-order saturation-split ECT, heights computed on the fly from x.v.
// Block = (chunk c, theta-half hf); 512 threads = (srow 0..31, t16 0..15).
// 512thr + 32KB LDS -> 2 blocks/CU = 16 waves/CU = 4 waves/SIMD (2x r10's
// occupancy; ect is gather-latency-bound).
// LDS hist [arr][g][bin][t16] = 32 KB; LDS int atomics only (deterministic;
// 16 t16-lanes of each quarter-wave hit distinct addresses).
// Simplices ordered [nodes | edges | faces] -> three branch-free loops.
// Flush = plain coalesced int4 stores into partial[bid][8192].
__global__ __launch_bounds__(512) void ect_kernel(const float* __restrict__ x,
    const float* __restrict__ v, const int* __restrict__ ei,
    const int* __restrict__ face, const int* __restrict__ batch,
    const float* __restrict__ lin, const int* __restrict__ scale_p,
    int* __restrict__ partial, int N, int E, int F, int M, int csz) {
  __shared__ alignas(16) int hist[8192];  // arr*4096 + g*512 + bin*16 + t16
  int tid = threadIdx.x, bid = blockIdx.x;
  int c = bid >> 1, hf = bid & 1;
#pragma unroll
  for (int i = 0; i < 4; ++i)
    ((int4*)hist)[tid + 512 * i] = int4{0, 0, 0, 0};
  __syncthreads();

  int t16 = tid & 15, srow = tid >> 4;    // srow 0..31
  int tt = (hf << 4) + t16;               // global theta
  float v0 = v[tt], v1 = v[32 + tt], v2 = v[64 + tt];
  int start = c * csz;
  int end = min(start + csz, M);

  float scale = (float)scale_p[0];
  float lin0 = lin[0];
  float step = (lin[31] - lin0) * (1.f / 31.f);
  float istep = 1.f / step;
  float Cl = scale * step * 1.44269504088896f;  // log2-slope per bin
  float w = 13.f / (scale * step);              // transition half-width (bins)

  auto dot3 = [&](int n) {
    return fmaf(x[3 * n], v0, fmaf(x[3 * n + 1], v1, x[3 * n + 2] * v2));
  };
  auto deposit = [&](float h, int g, int isn) {
    float kf = (h - lin0) * istep;
    int b0 = (int)ceilf(kf - w);
    int b1 = (int)floorf(kf + w);
    int fs = max(b1 + 1, 0);
    int gb = g << 9;
    if (fs <= 31) atomicAdd(&hist[gb + (fs << 4) + t16], isn);
    float q = Cl * kf;
    float fsn = (float)isn;
    int blo = max(b0, 0), bhi = min(b1, 31);
    for (int b = blo; b <= bhi; ++b) {
      float e2 = __builtin_amdgcn_exp2f(fmaf(-Cl, (float)b, q));
      float val = fsn * __builtin_amdgcn_rcpf(1.f + e2);
      atomicAdd(&hist[4096 + gb + (b << 4) + t16], (int)rintf(val * FPS));
    }
  };

  // nodes
  int e0 = min(end, N);
  for (int m = start + srow; m < e0; m += 32)
    deposit(dot3(m), batch[m], 1);
  // edges (max over 2 endpoints, sign -1)
  int s1 = max(start, N), e1 = min(end, N + E);
  for (int m = s1 + srow; m < e1; m += 32) {
    int e = m - N;
    int n0 = ei[e], n1 = ei[E + e];
    deposit(fmaxf(dot3(n0), dot3(n1)), batch[n0], -1);
  }
  // faces (max over 3 vertices, sign +1)
  int s2 = max(start, N + E);
  for (int m = s2 + srow; m < end; m += 32) {
    int f = m - N - E;
    int n0 = face[f], n1 = face[F + f], n2 = face[2 * F + f];
    deposit(fmaxf(fmaxf(dot3(n0), dot3(n1)), dot3(n2)), batch[n0], 1);
  }
  __syncthreads();
  int4* dst = (int4*)(partial + (size_t)bid * 8192);
  const int4* src = (const int4*)hist;
#pragma unroll
  for (int i = 0; i < 4; ++i)
    dst[tid + 512 * i] = src[tid + 512 * i];
}

// K2: tree reduce over chunks. 512 blocks: s = bid>>6 (0..7), cg = bid&63;
// cell cid = cg*256+tid; cid = hf*8192 + (arr*4096 + g*512 + bin*16 + t16).
// Plain coalesced loads/stores, no atomics.
__global__ __launch_bounds__(256) void reduce_kernel(const int* __restrict__ partial,
    int* __restrict__ part2) {
  int tid = threadIdx.x, bid = blockIdx.x;
  int s = bid >> 6, cg = bid & 63;
  int cid = cg * 256 + tid;
  int hf = cid >> 13, j = cid & 8191;
  int sum = 0;
  for (int cc = s; cc < NCH; cc += RSL)
    sum += partial[(size_t)(cc * 2 + hf) * 8192 + j];
  part2[s * 16384 + cid] = sum;
}

// K3: per-graph block (8 x 1024): sum RSL slices (plain loads), Hillis-Steele
// prefix of markers over bins, add fractional transitions, per-graph max,
// normalize, write out.
__global__ __launch_bounds__(1024) void fin_kernel(const int* __restrict__ part2,
    float* __restrict__ out) {
  __shared__ float sP[32][33];
  __shared__ float wmax[16];
  int g = blockIdx.x, tid = threadIdx.x;
  int b = tid >> 5, t = tid & 31;
  int hf = t >> 4, t16 = t & 15;
  int jc = (hf << 13) + (g << 9) + (b << 4) + t16;  // marker cell
  int ja = jc + 4096;                               // transition cell
  int sc = 0, sa = 0;
#pragma unroll
  for (int s = 0; s < RSL; ++s) {
    sc += part2[s * 16384 + jc];
    sa += part2[s * 16384 + ja];
  }
  sP[b][t] = (float)sc;
  __syncthreads();
#pragma unroll
  for (int st = 1; st < 32; st <<= 1) {
    float add = (b >= st) ? sP[b - st][t] : 0.f;
    __syncthreads();
    sP[b][t] += add;
    __syncthreads();
  }
  float r = sP[b][t] + (float)sa * (1.f / FPS);
  float m = r;
#pragma unroll
  for (int off = 32; off > 0; off >>= 1) m = fmaxf(m, __shfl_down(m, off));
  if ((tid & 63) == 0) wmax[tid >> 6] = m;
  __syncthreads();
  if (tid == 0) {
    float mm = wmax[0];
#pragma unroll
    for (int ww = 1; ww < 16; ++ww) mm = fmaxf(mm, wmax[ww]);
    wmax[0] = mm;
  }
  __syncthreads();
  out[(size_t)g * 1024 + tid] = r / wmax[0];
}

extern "C" void kernel_launch(void* const* d_in, const int* in_sizes, int n_in,
                              void* d_out, int out_size, void* d_ws, size_t ws_size,
                              hipStream_t stream) {
  const float* x     = (const float*)d_in[0];
  const float* v     = (const float*)d_in[1];
  const float* lin   = (const float*)d_in[2];
  const int*   ei    = (const int*)d_in[3];
  const int*   face  = (const int*)d_in[4];
  const int*   batch = (const int*)d_in[5];
  const int*   scale = (const int*)d_in[6];
  const int N = in_sizes[5];
  const int E = in_sizes[3] / 2;
  const int F = in_sizes[4] / 3;
  const int M = N + E + F;
  const int csz = (M + NCH - 1) / NCH;   // simplices per chunk (~704)

  int* partial = (int*)d_ws;                          // 2*NCH*8192 ints
  int* part2   = partial + (size_t)2 * NCH * 8192;    // RSL*16384 ints

  ect_kernel<<<2 * NCH, 512, 0, stream>>>(x, v, ei, face, batch, lin, scale,
                                          partial, N, E, F, M, csz);
  reduce_kernel<<<64 * RSL, 256, 0, stream>>>(partial, part2);
  fin_kernel<<<8, 1024, 0, stream>>>(part2, (float*)d_out);
}

// Round 12
// 33.332 us; speedup vs baseline: 2.6500x; 1.0583x over previous
//
#include <hip/hip_runtime.h>
#include <math.h>

#define NCH 256        // number of simplex chunks (grid_ect = 2*NCH = 512)
#define RSL 8          // reduction slices
#define FPS 32768.0f   // fixed-point scale 2^15 for transition sums

// K1: raw-order saturation-split ECT, heights computed on the fly from x.v.
// Block = (chunk c, theta-half hf); 1024 threads = (srow 0..63, t16 0..15).
// 1024thr x 2 blocks/CU = 2048 thr/CU = 8 waves/SIMD — hardware-max
// occupancy (ect is gather-latency-bound; r10->r11 doubling gave 1.35x).
// LDS hist [arr][g][bin][t16] = 32 KB; LDS int atomics only (deterministic;
// 16 t16-lanes of each quarter-wave hit distinct addresses).
// Simplices ordered [nodes | edges | faces] -> three branch-free loops.
// Flush = plain coalesced int4 stores into partial[bid][8192].
__global__ __launch_bounds__(1024) void ect_kernel(const float* __restrict__ x,
    const float* __restrict__ v, const int* __restrict__ ei,
    const int* __restrict__ face, const int* __restrict__ batch,
    const float* __restrict__ lin, const int* __restrict__ scale_p,
    int* __restrict__ partial, int N, int E, int F, int M, int csz) {
  __shared__ alignas(16) int hist[8192];  // arr*4096 + g*512 + bin*16 + t16
  int tid = threadIdx.x, bid = blockIdx.x;
  int c = bid >> 1, hf = bid & 1;
#pragma unroll
  for (int i = 0; i < 2; ++i)
    ((int4*)hist)[tid + 1024 * i] = int4{0, 0, 0, 0};
  __syncthreads();

  int t16 = tid & 15, srow = tid >> 4;    // srow 0..63
  int tt = (hf << 4) + t16;               // global theta
  float v0 = v[tt], v1 = v[32 + tt], v2 = v[64 + tt];
  int start = c * csz;
  int end = min(start + csz, M);

  float scale = (float)scale_p[0];
  float lin0 = lin[0];
  float step = (lin[31] - lin0) * (1.f / 31.f);
  float istep = 1.f / step;
  float Cl = scale * step * 1.44269504088896f;  // log2-slope per bin
  float w = 13.f / (scale * step);              // transition half-width (bins)

  auto dot3 = [&](int n) {
    return fmaf(x[3 * n], v0, fmaf(x[3 * n + 1], v1, x[3 * n + 2] * v2));
  };
  auto deposit = [&](float h, int g, int isn) {
    float kf = (h - lin0) * istep;
    int b0 = (int)ceilf(kf - w);
    int b1 = (int)floorf(kf + w);
    int fs = max(b1 + 1, 0);
    int gb = g << 9;
    if (fs <= 31) atomicAdd(&hist[gb + (fs << 4) + t16], isn);
    float q = Cl * kf;
    float fsn = (float)isn;
    int blo = max(b0, 0), bhi = min(b1, 31);
    for (int b = blo; b <= bhi; ++b) {
      float e2 = __builtin_amdgcn_exp2f(fmaf(-Cl, (float)b, q));
      float val = fsn * __builtin_amdgcn_rcpf(1.f + e2);
      atomicAdd(&hist[4096 + gb + (b << 4) + t16], (int)rintf(val * FPS));
    }
  };

  // nodes
  int e0 = min(end, N);
  for (int m = start + srow; m < e0; m += 64)
    deposit(dot3(m), batch[m], 1);
  // edges (max over 2 endpoints, sign -1)
  int s1 = max(start, N), e1 = min(end, N + E);
  for (int m = s1 + srow; m < e1; m += 64) {
    int e = m - N;
    int n0 = ei[e], n1 = ei[E + e];
    deposit(fmaxf(dot3(n0), dot3(n1)), batch[n0], -1);
  }
  // faces (max over 3 vertices, sign +1)
  int s2 = max(start, N + E);
  for (int m = s2 + srow; m < end; m += 64) {
    int f = m - N - E;
    int n0 = face[f], n1 = face[F + f], n2 = face[2 * F + f];
    deposit(fmaxf(fmaxf(dot3(n0), dot3(n1)), dot3(n2)), batch[n0], 1);
  }
  __syncthreads();
  int4* dst = (int4*)(partial + (size_t)bid * 8192);
  const int4* src = (const int4*)hist;
#pragma unroll
  for (int i = 0; i < 2; ++i)
    dst[tid + 1024 * i] = src[tid + 1024 * i];
}

// K2: tree reduce over chunks. 512 blocks: s = bid>>6 (0..7), cg = bid&63;
// cell cid = cg*256+tid; cid = hf*8192 + (arr*4096 + g*512 + bin*16 + t16).
// Plain coalesced loads/stores, no atomics.
__global__ __launch_bounds__(256) void reduce_kernel(const int* __restrict__ partial,
    int* __restrict__ part2) {
  int tid = threadIdx.x, bid = blockIdx.x;
  int s = bid >> 6, cg = bid & 63;
  int cid = cg * 256 + tid;
  int hf = cid >> 13, j = cid & 8191;
  int sum = 0;
  for (int cc = s; cc < NCH; cc += RSL)
    sum += partial[(size_t)(cc * 2 + hf) * 8192 + j];
  part2[s * 16384 + cid] = sum;
}

// K3: per-graph block (8 x 1024): sum RSL slices (plain loads), Hillis-Steele
// prefix of markers over bins, add fractional transitions, per-graph max,
// normalize, write out.
__global__ __launch_bounds__(1024) void fin_kernel(const int* __restrict__ part2,
    float* __restrict__ out) {
  __shared__ float sP[32][33];
  __shared__ float wmax[16];
  int g = blockIdx.x, tid = threadIdx.x;
  int b = tid >> 5, t = tid & 31;
  int hf = t >> 4, t16 = t & 15;
  int jc = (hf << 13) + (g << 9) + (b << 4) + t16;  // marker cell
  int ja = jc + 4096;                               // transition cell
  int sc = 0, sa = 0;
#pragma unroll
  for (int s = 0; s < RSL; ++s) {
    sc += part2[s * 16384 + jc];
    sa += part2[s * 16384 + ja];
  }
  sP[b][t] = (float)sc;
  __syncthreads();
#pragma unroll
  for (int st = 1; st < 32; st <<= 1) {
    float add = (b >= st) ? sP[b - st][t] : 0.f;
    __syncthreads();
    sP[b][t] += add;
    __syncthreads();
  }
  float r = sP[b][t] + (float)sa * (1.f / FPS);
  float m = r;
#pragma unroll
  for (int off = 32; off > 0; off >>= 1) m = fmaxf(m, __shfl_down(m, off));
  if ((tid & 63) == 0) wmax[tid >> 6] = m;
  __syncthreads();
  if (tid == 0) {
    float mm = wmax[0];
#pragma unroll
    for (int ww = 1; ww < 16; ++ww) mm = fmaxf(mm, wmax[ww]);
    wmax[0] = mm;
  }
  __syncthreads();
  out[(size_t)g * 1024 + tid] = r / wmax[0];
}

extern "C" void kernel_launch(void* const* d_in, const int* in_sizes, int n_in,
                              void* d_out, int out_size, void* d_ws, size_t ws_size,
                              hipStream_t stream) {
  const float* x     = (const float*)d_in[0];
  const float* v     = (const float*)d_in[1];
  const float* lin   = (const float*)d_in[2];
  const int*   ei    = (const int*)d_in[3];
  const int*   face  = (const int*)d_in[4];
  const int*   batch = (const int*)d_in[5];
  const int*   scale = (const int*)d_in[6];
  const int N = in_sizes[5];
  const int E = in_sizes[3] / 2;
  const int F = in_sizes[4] / 3;
  const int M = N + E + F;
  const int csz = (M + NCH - 1) / NCH;   // simplices per chunk (~704)

  int* partial = (int*)d_ws;                          // 2*NCH*8192 ints
  int* part2   = partial + (size_t)2 * NCH * 8192;    // RSL*16384 ints

  ect_kernel<<<2 * NCH, 1024, 0, stream>>>(x, v, ei, face, batch, lin, scale,
                                           partial, N, E, F, M, csz);
  reduce_kernel<<<64 * RSL, 256, 0, stream>>>(partial, part2);
  fin_kernel<<<8, 1024, 0, stream>>>(part2, (float*)d_out);
}